// Round 6
// baseline (1007.960 us; speedup 1.0000x reference)
//
#include <hip/hip_runtime.h>
#include <math.h>

// ---------------- complex helpers (float2 = re,im) ----------------
typedef float2 cf;

__device__ __forceinline__ cf mkc(float x, float y){ return make_float2(x,y); }
__device__ __forceinline__ cf lo4(float4 v){ return mkc(v.x, v.y); }
__device__ __forceinline__ cf hi4(float4 v){ return mkc(v.z, v.w); }

// acc += a*b
__device__ __forceinline__ void cmad(cf& acc, cf a, cf b){
    acc.x = fmaf(a.x, b.x, fmaf(-a.y, b.y, acc.x));
    acc.y = fmaf(a.x, b.y, fmaf( a.y, b.x, acc.y));
}
// acc += conj(a)*b
__device__ __forceinline__ void cmadc(cf& acc, cf a, cf b){
    acc.x = fmaf(a.x, b.x, fmaf( a.y, b.y, acc.x));
    acc.y = fmaf(a.x, b.y, fmaf(-a.y, b.x, acc.y));
}
// acc += a*conj(b)
__device__ __forceinline__ void cmad_bc(cf& acc, cf a, cf b){
    acc.x = fmaf(a.x, b.x, fmaf( a.y, b.y, acc.x));
    acc.y = fmaf(a.y, b.x, fmaf(-a.x, b.y, acc.y));
}
// acc += conj(a)*conj(b)
__device__ __forceinline__ void cmad_cc(cf& acc, cf a, cf b){
    acc.x = fmaf(a.x, b.x, fmaf(-a.y, b.y, acc.x));
    acc.y = fmaf(-a.x, b.y, fmaf(-a.y, b.x, acc.y));
}
// principal complex sqrt (numpy branch conventions)
__device__ __forceinline__ cf csqrtf2(cf z){
    float x = z.x, y = z.y;
    float r = hypotf(x, y);
    if (r == 0.0f) return mkc(0.f, 0.f);
    if (x >= 0.0f){
        float t = sqrtf(0.5f*(r + x));
        return mkc(t, 0.5f*y/t);
    } else {
        float t = sqrtf(0.5f*(r - x));
        return mkc(0.5f*fabsf(y)/t, copysignf(t, y));
    }
}
// a / b
__device__ __forceinline__ cf cdiv(cf a, cf b){
    float inv = 1.0f/(b.x*b.x + b.y*b.y);
    return mkc((a.x*b.x + a.y*b.y)*inv, (a.y*b.x - a.x*b.y)*inv);
}

#define LN2F  0.69314718055994530942f
#define BETA_ 0.9f
#define OMB_  0.1f
#define EPS_  1e-8f
#define ETAF_ 0.01f
#define ETAW_ 0.01f

#define MM_S 66   /* sMm row stride (cf) */
#define F_S  18   /* sF / sMF row stride */
#define FT_S 66   /* sFT row stride */
#define H_S  66   /* sH row stride */
#define U_S  18   /* sU row stride */
#define V_S  18   /* sV row stride */

__device__ __forceinline__ float readScalarF(const int* p){
    int iv = *p;
    if (iv >= 0 && iv < 1000000) return (float)iv;
    return __int_as_float(iv);
}
__device__ __forceinline__ int readScalarI(const int* p){
    int iv = *p;
    if (iv >= 0 && iv < 1000000) return iv;
    return (int)(__int_as_float(iv) + 0.5f);
}

// per-sub-batch 256-thread reduce; block-wide barrier (all subs call uniformly)
__device__ __forceinline__ float blockReduceSum(float v, float* slot, int t){
    #pragma unroll
    for (int o = 32; o > 0; o >>= 1) v += __shfl_down(v, o, 64);
    if ((t & 63) == 0) slot[t >> 6] = v;
    __syncthreads();
    return slot[0] + slot[1] + slot[2] + slot[3];
}
__device__ __forceinline__ float2 blockReduceSum2(float a, float b2, float* sA, float* sB, int t){
    #pragma unroll
    for (int o = 32; o > 0; o >>= 1){ a += __shfl_down(a, o, 64); b2 += __shfl_down(b2, o, 64); }
    if ((t & 63) == 0){ sA[t >> 6] = a; sB[t >> 6] = b2; }
    __syncthreads();
    return make_float2(sA[0]+sA[1]+sA[2]+sA[3], sB[0]+sB[1]+sB[2]+sB[3]);
}

// MF = Mm @ F via FT (row-contiguous b128). thread (nb=t>>4, j=t&15), 4 rows.
__device__ __forceinline__ void computeMF_T(const cf* sMm, const cf* sFT, cf* sMF, int t){
    int j = t & 15, nb = t >> 4;
    cf a0=mkc(0,0), a1=mkc(0,0), a2=mkc(0,0), a3=mkc(0,0);
    const float4* ftrow = (const float4*)(sFT + j*FT_S);
    #pragma unroll
    for (int kkb = 0; kkb < 4; kkb++){
        cf f[16];
        #pragma unroll
        for (int q = 0; q < 8; q++){
            float4 v = ftrow[kkb*8+q];
            f[2*q] = lo4(v); f[2*q+1] = hi4(v);
        }
        const float4* m0 = (const float4*)(sMm + (nb    )*MM_S + kkb*16);
        const float4* m1 = (const float4*)(sMm + (nb+16 )*MM_S + kkb*16);
        const float4* m2 = (const float4*)(sMm + (nb+32 )*MM_S + kkb*16);
        const float4* m3 = (const float4*)(sMm + (nb+48 )*MM_S + kkb*16);
        #pragma unroll
        for (int q = 0; q < 8; q++){
            float4 v0 = m0[q], v1 = m1[q], v2 = m2[q], v3 = m3[q];
            cmad(a0, lo4(v0), f[2*q]); cmad(a0, hi4(v0), f[2*q+1]);
            cmad(a1, lo4(v1), f[2*q]); cmad(a1, hi4(v1), f[2*q+1]);
            cmad(a2, lo4(v2), f[2*q]); cmad(a2, hi4(v2), f[2*q+1]);
            cmad(a3, lo4(v3), f[2*q]); cmad(a3, hi4(v3), f[2*q+1]);
        }
    }
    sMF[(nb   )*F_S+j]=a0; sMF[(nb+16)*F_S+j]=a1;
    sMF[(nb+32)*F_S+j]=a2; sMF[(nb+48)*F_S+j]=a3;
}

// u[m][j] = sum_n conj(H[m,n]) F[n,j], split-K over 256 threads
__device__ __forceinline__ void uRefresh(const cf* sH, const cf* sFT, cf* sU, int t){
    int h = t & 1, j = (t >> 1) & 15, m = t >> 5;
    const float4* hp = (const float4*)(sH  + m*H_S);
    const float4* fp = (const float4*)(sFT + j*FT_S);
    cf acc = mkc(0,0);
    #pragma unroll
    for (int q = 0; q < 16; q++){
        int c = 2*q + h;
        float4 hv = hp[c], fv = fp[c];
        cmadc(acc, lo4(hv), lo4(fv));
        cmadc(acc, hi4(hv), hi4(fv));
    }
    acc.x += __shfl_xor(acc.x, 1, 64);
    acc.y += __shfl_xor(acc.y, 1, 64);
    if (h == 0) sU[m*U_S+j] = acc;
}

// FW = F@W from FT columns; FW kept in registers; returns |FW|^2 partial
__device__ __forceinline__ float fwPartialT(const cf* sFT, const cf* sW, cf* fw0, cf* fw1, int t){
    int k = t & 7, nb = t >> 3;          // nb in 0..31; rows nb, nb+32
    cf a0 = mkc(0,0), a1 = mkc(0,0);
    #pragma unroll
    for (int r = 0; r < 16; r++){
        cf w = sW[r*8+k];
        cmad(a0, sFT[r*FT_S + nb     ], w);
        cmad(a1, sFT[r*FT_S + nb + 32], w);
    }
    *fw0 = a0; *fw1 = a1;
    return a0.x*a0.x + a0.y*a0.y + a1.x*a1.x + a1.y*a1.y;
}

// trc partial via Y = MF@W with register FW
__device__ __forceinline__ float trcViaMFr(const cf* sMF, const cf* sW, cf fw0, cf fw1, int t){
    int k = t & 7, nb = t >> 3;
    cf wcol[16];
    #pragma unroll
    for (int r = 0; r < 16; r++) wcol[r] = sW[r*8+k];
    float ptrc = 0.f;
    {
        const float4* mr = (const float4*)(sMF + nb*F_S);
        cf acc = mkc(0,0);
        #pragma unroll
        for (int q = 0; q < 8; q++){
            float4 v = mr[q];
            cmad(acc, lo4(v), wcol[2*q]); cmad(acc, hi4(v), wcol[2*q+1]);
        }
        ptrc += fw0.x*acc.x + fw0.y*acc.y;
    }
    {
        const float4* mr = (const float4*)(sMF + (nb+32)*F_S);
        cf acc = mkc(0,0);
        #pragma unroll
        for (int q = 0; q < 8; q++){
            float4 v = mr[q];
            cmad(acc, lo4(v), wcol[2*q]); cmad(acc, hi4(v), wcol[2*q+1]);
        }
        ptrc += fw1.x*acc.x + fw1.y*acc.y;
    }
    return ptrc;
}

// sum-rate on wave 3 of each sub (t>=192); result -> *sRateVal
__device__ __forceinline__ void ratesWave3(const cf* sU, const cf* sW, float mul,
                                           float* sRateVal, int t){
    if (t < 192) return;
    int l = t - 192, m = l >> 3, k = l & 7;
    cf acc = mkc(0,0);
    #pragma unroll
    for (int j = 0; j < 16; j++) cmad(acc, sU[m*U_S+j], sW[j*8+k]);
    float p = acc.x*acc.x + acc.y*acc.y;
    float tot = p;
    #pragma unroll
    for (int mask = 4; mask >= 1; mask >>= 1) tot += __shfl_xor(tot, mask, 8);
    float sig = __shfl(p, 9*m, 64);
    float rate = log2f(1.0f + (mul*sig)/fmaf(mul, tot - sig, 1.0f));
    float val = (k == 0) ? rate : 0.0f;
    #pragma unroll
    for (int mask = 32; mask >= 1; mask >>= 1) val += __shfl_xor(val, mask, 64);
    if (l == 0) *sRateVal = val;
}

// ---------------- prep: Mm = A_dot^H @ R_N_inv @ A_dot -> ws ----------------
__global__ __launch_bounds__(256) void pga_prep(
    const float* __restrict__ Ar, const float* __restrict__ Ai,
    const float* __restrict__ Rr, const float* __restrict__ Ri,
    cf* __restrict__ Mm)
{
    __shared__ cf sA[4096];
    __shared__ cf Tc[512];
    int tid = threadIdx.x;
    for (int idx = tid; idx < 4096; idx += 256)
        sA[idx] = mkc(Ar[idx], Ai[idx]);
    __syncthreads();
    for (int jb = 0; jb < 8; jb++){
        int j0 = jb*8;
        #pragma unroll
        for (int rep = 0; rep < 2; rep++){
            int idx = tid + rep*256;
            int p = idx >> 3, jc = idx & 7;
            cf acc = mkc(0,0);
            for (int q = 0; q < 64; q++){
                cf rv = mkc(Rr[p*64+q], Ri[p*64+q]);
                cmad(acc, rv, sA[q*64 + j0 + jc]);
            }
            Tc[idx] = acc;
        }
        __syncthreads();
        #pragma unroll
        for (int rep = 0; rep < 2; rep++){
            int idx = tid + rep*256;
            int i = idx >> 3, jc = idx & 7;
            cf acc = mkc(0,0);
            for (int p = 0; p < 64; p++)
                cmadc(acc, sA[p*64+i], Tc[p*8+jc]);
            Mm[i*64 + j0 + jc] = acc;
        }
        __syncthreads();
    }
}

// ================= mega-kernel: 4 batch elements per 1024-thread block =================
// Dynamic LDS: 33792 (Mm, shared) + 4*29696 (per-batch pools) = 152576 B -> 1 block/CU,
// 16 waves/CU (4/SIMD). All 1024 batches resident at once (grid 256 = depth-1 schedule).
#define POOL_STRIDE 29696
#define MEGA_LDS (33792 + 4*POOL_STRIDE)

__global__ __launch_bounds__(1024) void pga_main4(
    const float* __restrict__ Hre, const float* __restrict__ Him,
    const float* __restrict__ F0re, const float* __restrict__ F0im,
    const float* __restrict__ W0re, const float* __restrict__ W0im,
    const float* __restrict__ Ar, const float* __restrict__ Ai,
    const float* __restrict__ Rr, const float* __restrict__ Ri,
    const cf* __restrict__ MmGlobal,
    const float* __restrict__ xi0p,
    const int* __restrict__ Ptp, const int* __restrict__ noutp, const int* __restrict__ ninnp,
    float* __restrict__ out, int B, int cplx)
{
    extern __shared__ __align__(16) char smem[];
    const int tidb = threadIdx.x;
    const int sub  = tidb >> 8;      // 0..3 batch slot
    const int t    = tidb & 255;     // per-batch thread id
    const int b    = blockIdx.x*4 + sub;
    const bool active = (b < B);
    const int be = active ? b : 0;

    cf* sMm = (cf*)smem;                         // 64 x 66 (33792 B, shared)
    char* pool = smem + 33792 + sub*POOL_STRIDE;
    cf* sMF   = (cf*)(pool + 0);       // 64 x 18  (9216)
    cf* sFT   = (cf*)(pool + 9216);    // 16 x 66  (8448)
    cf* sH    = (cf*)(pool + 17664);   // 8 x 66   (4224)
    cf* sW    = (cf*)(pool + 21888);   // [r*8+m]  (1024)
    cf* sV    = (cf*)(pool + 22912);   // 16 x 18  (2304)
    cf* sU    = (cf*)(pool + 25216);   // 8 x 18   (1152)
    cf* sRow  = (cf*)(pool + 26368);   // [m*16+j] (1024)
    cf* sFHMF = (cf*)(pool + 27392);   // 16 x 17  (2176)
    cf* sCoefC= (cf*)(pool + 29568);   // [8]      (64)
    float* sRed     = (float*)(pool + 29632);   // 12 floats
    float* sRateVal = (float*)(pool + 29680);

    const float Pt    = readScalarF(Ptp);
    const int n_outer = readScalarI(noutp);
    const int n_inner = readScalarI(ninnp);
    const float xi0   = xi0p[0];
    const int nt = n_outer * (n_inner + 1);
    const float cxi = 2.0f*xi0*xi0;

    float* outR = out;
    float* outC = out + (size_t)B * nt;
    float* outF = out + (size_t)2 * B * nt;
    float* outW = outF + (cplx ? (size_t)B * 2048 : (size_t)B * 1024);

    // ---- Mm into shared LDS (block-wide) ----
    if (MmGlobal){
        for (int idx = tidb; idx < 4096; idx += 1024){
            int r = idx >> 6, c = idx & 63;
            sMm[r*MM_S+c] = MmGlobal[idx];
        }
    } else {
        cf* sA = (cf*)(smem + 33792);            // overlay over pools (32768 B)
        cf* Tc = (cf*)(smem + 33792 + 32768);    // 4096 B
        for (int idx = tidb; idx < 4096; idx += 1024)
            sA[idx] = mkc(Ar[idx], Ai[idx]);
        __syncthreads();
        for (int jb = 0; jb < 8; jb++){
            int j0 = jb*8;
            if (tidb < 512){
                int p = tidb >> 3, jc = tidb & 7;
                cf acc = mkc(0,0);
                for (int q = 0; q < 64; q++){
                    cf rv = mkc(Rr[p*64+q], Ri[p*64+q]);
                    cmad(acc, rv, sA[q*64 + j0 + jc]);
                }
                Tc[tidb] = acc;
            }
            __syncthreads();
            if (tidb < 512){
                int i2 = tidb >> 3, jc = tidb & 7;
                cf acc = mkc(0,0);
                for (int p = 0; p < 64; p++)
                    cmadc(acc, sA[p*64+i2], Tc[p*8+jc]);
                sMm[i2*MM_S + j0 + jc] = acc;
            }
            __syncthreads();
        }
    }
    __syncthreads();

    // ---- load H, F (projected -> sFT), W ----
    cf fsf[4]; cf ssw = mkc(0.f, 0.f);
    {
        const float* hr = Hre + (size_t)be*512;
        const float* hi = Him + (size_t)be*512;
        for (int idx = t; idx < 512; idx += 256){
            int m = idx >> 6, n = idx & 63;
            sH[m*H_S+n] = mkc(hr[idx], hi[idx]);
        }
        const float* fr = F0re + (size_t)be*1024;
        const float* fi = F0im + (size_t)be*1024;
        for (int idx = t; idx < 1024; idx += 256){
            int n = idx >> 4, r = idx & 15;
            float re = fr[idx], im = fi[idx];
            float mag = hypotf(re, im);
            cf f = (mag > 1e-12f) ? mkc(re/mag, im/mag) : mkc(0.f, 0.f);
            sFT[r*FT_S+n] = f;
        }
        if (t < 128)
            sW[t] = mkc(W0re[(size_t)be*128 + t], W0im[(size_t)be*128 + t]);
        #pragma unroll
        for (int rep = 0; rep < 4; rep++) fsf[rep] = mkc(0.f, 0.f);
    }
    __syncthreads();

    // ---- init: u, W-normalize, MF ----
    uRefresh(sH, sFT, sU, t);
    {
        cf fwa, fwb;
        float pw0 = blockReduceSum(fwPartialT(sFT, sW, &fwa, &fwb, t), sRed+0, t);
        float s0 = sqrtf(Pt / pw0);
        if (t < 128){ cf w = sW[t]; sW[t] = mkc(w.x*s0, w.y*s0); }
    }
    computeMF_T(sMm, sFT, sMF, t);
    __syncthreads();

    float sp = 1.0f, sp2 = 1.0f;   // pending normalize scale (true F = sp * stored F)

    for (int ii = 0; ii < n_outer; ii++){
        // V = W W^H
        {
            int i = t >> 4, jx = t & 15;
            cf acc = mkc(0,0);
            #pragma unroll
            for (int k = 0; k < 8; k++) cmad_bc(acc, sW[i*8+k], sW[jx*8+k]);
            sV[i*V_S+jx] = acc;
        }
        __syncthreads();

        for (int jj = 0; jj < n_inner; jj++){
            const int j = t & 15, nb = t >> 4;

            cf vrow[16];
            {
                const float4* vp = (const float4*)(sV + j*V_S);
                #pragma unroll
                for (int q = 0; q < 8; q++){
                    float4 v = vp[q];
                    vrow[2*q] = lo4(v); vrow[2*q+1] = hi4(v);
                }
            }
            // G = MF@V (regs) + trace partial
            float ptr_ = 0.f;
            cf G[4];
            #pragma unroll
            for (int rep = 0; rep < 4; rep++){
                int n = nb + rep*16;
                const float4* mr = (const float4*)(sMF + n*F_S);
                cf acc = mkc(0,0);
                #pragma unroll
                for (int q = 0; q < 8; q++){
                    float4 v = mr[q];
                    cmad_bc(acc, lo4(v), vrow[2*q]); cmad_bc(acc, hi4(v), vrow[2*q+1]);
                }
                G[rep] = acc;
                cf f = sFT[j*FT_S+n];
                ptr_ += f.x*acc.x + f.y*acc.y;
            }
            // coef/row phase (t<128), sp-folded
            if (t < 128){
                int m = t >> 4;
                const float4* up = (const float4*)(sU + m*U_S);
                cf t2 = mkc(0,0);
                #pragma unroll
                for (int q = 0; q < 8; q++){
                    float4 uv = up[q];
                    cmad_bc(t2, lo4(uv), vrow[2*q]); cmad_bc(t2, hi4(uv), vrow[2*q+1]);
                }
                cf u = sU[m*U_S+j];
                float qv = t2.x*u.x + t2.y*u.y;
                cf c = mkc(0,0); cmad(c, u, sW[j*8+m]);
                #pragma unroll
                for (int mask = 8; mask >= 1; mask >>= 1){
                    qv  += __shfl_xor(qv,  mask, 16);
                    c.x += __shfl_xor(c.x, mask, 16);
                    c.y += __shfl_xor(c.y, mask, 16);
                }
                float cc = c.x*c.x + c.y*c.y;
                float inv1 = 1.0f/(LN2F*(sp2*qv + 1.0f) + 1e-4f);
                float inv2 = 1.0f/(LN2F*(sp2*(qv - cc) + 1.0f) + 1e-4f);
                float a = inv1 - inv2;
                cf ci = mkc(c.x*inv2, c.y*inv2);
                cf row = mkc(t2.x*a, t2.y*a);
                cmad_bc(row, ci, sW[j*8+m]);
                sRow[t] = row;
            }
            if (jj > 0) ratesWave3(sU, sW, sp2, sRateVal, t);
            float tr = blockReduceSum(ptr_, sRed+0, t);   // barrier B1
            if (jj > 0 && active && t == 0){
                int tt = ii*(n_inner+1) + jj;
                size_t base = (size_t)b*nt;
                outR[base + tt] = *sRateVal;
                outC[base + tt] = 1.0f/(cxi*(sp2*tr) + 1e-12f);
            }

            // D: gF (sp-folded) + RMSProp + F update (sFT only)
            {
                float hinv = 0.5f/(sp*tr);
                cf rowj[8];
                #pragma unroll
                for (int m = 0; m < 8; m++){
                    cf r = sRow[m*16+j];
                    rowj[m] = mkc(sp*r.x, sp*r.y);
                }
                #pragma unroll
                for (int rep = 0; rep < 4; rep++){
                    int n = nb + rep*16;
                    cf g = mkc(G[rep].x*hinv, G[rep].y*hinv);
                    #pragma unroll
                    for (int m = 0; m < 8; m++) cmad(g, sH[m*H_S+n], rowj[m]);
                    cf sf = fsf[rep];
                    sf.x = BETA_*sf.x + OMB_*g.x;
                    sf.y = BETA_*sf.y + OMB_*g.y;
                    fsf[rep] = sf;
                    cf d = csqrtf2(sf); d.x += EPS_;
                    cf upd = cdiv(g, d);
                    cf f = sFT[j*FT_S+n];
                    cf fn = mkc(fmaf(ETAF_, upd.x, sp*f.x), fmaf(ETAF_, upd.y, sp*f.y));
                    sFT[j*FT_S+n] = fn;
                }
            }
            __syncthreads();                                 // barrier B2

            // E: MF recompute, FW/power partial (reg FW), u refresh
            computeMF_T(sMm, sFT, sMF, t);
            cf fwa, fwb;
            float part = fwPartialT(sFT, sW, &fwa, &fwb, t);
            uRefresh(sH, sFT, sU, t);
            float pw = blockReduceSum(part, sRed+4, t);      // barrier B3
            float s = sqrtf(Pt / pw);
            sp = s; sp2 = s*s;

            if (jj == n_inner-1){
                float ptrl = 0.f;
                #pragma unroll
                for (int rep = 0; rep < 4; rep++){
                    int n = nb + rep*16;
                    const float4* mr = (const float4*)(sMF + n*F_S);
                    cf acc = mkc(0,0);
                    #pragma unroll
                    for (int q = 0; q < 8; q++){
                        float4 v = mr[q];
                        cmad_bc(acc, lo4(v), vrow[2*q]); cmad_bc(acc, hi4(v), vrow[2*q+1]);
                    }
                    cf f = sFT[j*FT_S+n];
                    ptrl += f.x*acc.x + f.y*acc.y;
                }
                ratesWave3(sU, sW, sp2, sRateVal, t);
                float trl = blockReduceSum(ptrl, sRed+8, t); // barrier B4
                if (active && t == 0){
                    int tt = ii*(n_inner+1) + n_inner;
                    size_t base = (size_t)b*nt;
                    outR[base + tt] = *sRateVal;
                    outC[base + tt] = 1.0f/(cxi*(sp2*trl) + 1e-12f);
                }
            }
        } // jj

        // ---- outer step ----
        const int j = t & 15, nb = t >> 4;
        // O1: project F
        {
            #pragma unroll
            for (int rep = 0; rep < 4; rep++){
                int n = nb + rep*16;
                cf f = sFT[j*FT_S+n];
                float mag = hypotf(f.x, f.y);
                cf fp = (sp*mag > 1e-12f) ? mkc(f.x/mag, f.y/mag) : mkc(0.f, 0.f);
                sFT[j*FT_S+n] = fp;
            }
            sp = 1.0f; sp2 = 1.0f;
        }
        __syncthreads();
        // O2: MF ; u
        computeMF_T(sMm, sFT, sMF, t);
        uRefresh(sH, sFT, sU, t);
        __syncthreads();
        // O3: FHMF + tr partial ; coef via shuffles
        float ptr2;
        {
            int i = t >> 4;
            const float4* fti = (const float4*)(sFT + i*FT_S);
            cf acc = mkc(0,0);
            #pragma unroll
            for (int q = 0; q < 32; q++){
                float4 fv = fti[q];
                cmadc(acc, lo4(fv), sMF[(2*q  )*F_S+j]);
                cmadc(acc, hi4(fv), sMF[(2*q+1)*F_S+j]);
            }
            sFHMF[i*17+j] = acc;
            cf v = sV[j*V_S+i];
            ptr2 = acc.x*v.x - acc.y*v.y;
        }
        if (t < 128){
            int m = t >> 4, r = t & 15;
            cf u_mr = sU[m*U_S+r];
            const float4* up = (const float4*)(sU + m*U_S);
            cf t2 = mkc(0,0);
            #pragma unroll
            for (int q = 0; q < 8; q++){
                float4 uv = up[q];
                cmad_cc(t2, sV[(2*q)*V_S+r],   lo4(uv));
                cmad_cc(t2, sV[(2*q+1)*V_S+r], hi4(uv));
            }
            float trm = u_mr.x*t2.x - u_mr.y*t2.y;
            cf a = mkc(0,0); cmad(a, u_mr, sW[r*8+m]);
            #pragma unroll
            for (int mask = 8; mask >= 1; mask >>= 1){
                trm += __shfl_xor(trm, mask, 16);
                a.x += __shfl_xor(a.x, mask, 16);
                a.y += __shfl_xor(a.y, mask, 16);
            }
            if (r == 0){
                float invd = 1.0f/(LN2F*(trm + 1.0f)*8.0f);
                sCoefC[m] = mkc(a.x*invd, a.y*invd);
            }
        }
        float trW = blockReduceSum(ptr2, sRed+0, t);
        // O5a: gW in regs
        cf gw = mkc(0,0);
        if (t < 128){
            int i2 = t >> 3, mm = t & 7;
            cf acc = mkc(0,0);
            #pragma unroll
            for (int j2 = 0; j2 < 16; j2++) cmad(acc, sFHMF[i2*17+j2], sW[j2*8+mm]);
            float hinv = 0.5f / trW;
            gw = mkc(acc.x*hinv, acc.y*hinv);
            cmadc(gw, sU[mm*U_S+i2], sCoefC[mm]);
        }
        __syncthreads();
        // O6: RMSProp W update
        if (t < 128){
            cf sw = ssw;
            sw.x = BETA_*sw.x + OMB_*gw.x;
            sw.y = BETA_*sw.y + OMB_*gw.y;
            ssw = sw;
            cf d = csqrtf2(sw); d.x += EPS_;
            cf upd = cdiv(gw, d);
            cf w = sW[t];
            w.x = fmaf(ETAW_, upd.x, w.x);
            w.y = fmaf(ETAW_, upd.y, w.y);
            sW[t] = w;
        }
        __syncthreads();
        // O7/O8: power + crb trace
        cf fwa2, fwb2;
        float part2 = fwPartialT(sFT, sW, &fwa2, &fwb2, t);
        float ptrc2 = trcViaMFr(sMF, sW, fwa2, fwb2, t);
        float2 pr = blockReduceSum2(part2, ptrc2, sRed+4, sRed+8, t);
        float s2 = sqrtf(Pt / pr.x);
        float s2sq = s2*s2;
        ratesWave3(sU, sW, s2sq, sRateVal, t);
        __syncthreads();
        // O9/O10: scale W, write tracking slot
        if (t < 128){
            cf w = sW[t];
            sW[t] = mkc(w.x*s2, w.y*s2);
        }
        if (active && t == 0){
            int tt = ii*(n_inner+1);
            size_t base = (size_t)b*nt;
            outR[base + tt] = *sRateVal;
            outC[base + tt] = 1.0f/(cxi*(s2sq*pr.y) + 1e-12f);
        }
        __syncthreads();
    } // ii

    // ---- write final F, W ----
    if (active){
        int j = t & 15, nb = t >> 4;
        if (cplx){
            #pragma unroll
            for (int rep = 0; rep < 4; rep++){
                int n = nb + rep*16;
                cf f = sFT[j*FT_S+n];
                size_t o = ((size_t)b*1024 + (size_t)(t + rep*256))*2;
                outF[o]   = f.x;
                outF[o+1] = f.y;
            }
            if (t < 128){
                cf w = sW[t];
                size_t o = ((size_t)b*128 + t)*2;
                outW[o]   = w.x;
                outW[o+1] = w.y;
            }
        } else {
            #pragma unroll
            for (int rep = 0; rep < 4; rep++){
                int n = nb + rep*16;
                outF[(size_t)b*1024 + (size_t)(t + rep*256)] = sFT[j*FT_S+n].x;
            }
            if (t < 128)
                outW[(size_t)b*128 + t] = sW[t].x;
        }
    }
}

// ================= fallback: round-5 verified kernel (256 thr, 1 batch/block) =================
__global__ __launch_bounds__(256) void pga_main(
    const float* __restrict__ Hre, const float* __restrict__ Him,
    const float* __restrict__ F0re, const float* __restrict__ F0im,
    const float* __restrict__ W0re, const float* __restrict__ W0im,
    const float* __restrict__ Ar, const float* __restrict__ Ai,
    const float* __restrict__ Rr, const float* __restrict__ Ri,
    const cf* __restrict__ MmGlobal,
    const float* __restrict__ xi0p,
    const int* __restrict__ Ptp, const int* __restrict__ noutp, const int* __restrict__ ninnp,
    float* __restrict__ out, int B, int cplx)
{
    const int tid = threadIdx.x;
    const int b = blockIdx.x;

    __shared__ __align__(16) char sPool[76736];
    __shared__ float sRedS[12];
    __shared__ float sRateValS;

    cf* sMm   = (cf*)(sPool + 0);
    cf* sF    = (cf*)(sPool + 33792);
    cf* sMF   = (cf*)(sPool + 43008);
    cf* sFT   = (cf*)(sPool + 52224);
    cf* sH    = (cf*)(sPool + 60672);
    cf* sW    = (cf*)(sPool + 64896);
    cf* sV    = (cf*)(sPool + 65920);
    cf* sU    = (cf*)(sPool + 68224);
    cf* sRow  = (cf*)(sPool + 69376);
    cf* sFHMF = (cf*)(sPool + 70400);
    cf* sFW   = (cf*)(sPool + 72576);
    cf* sCoefC= (cf*)(sPool + 76672);

    const float Pt    = readScalarF(Ptp);
    const int n_outer = readScalarI(noutp);
    const int n_inner = readScalarI(ninnp);
    const float xi0   = xi0p[0];
    const int nt = n_outer * (n_inner + 1);
    const float cxi = 2.0f*xi0*xi0;

    float* outR = out;
    float* outC = out + (size_t)B * nt;
    float* outF = out + (size_t)2 * B * nt;
    float* outW = outF + (cplx ? (size_t)B * 2048 : (size_t)B * 1024);

    if (MmGlobal){
        for (int idx = tid; idx < 4096; idx += 256){
            int r = idx >> 6, c = idx & 63;
            sMm[r*MM_S+c] = MmGlobal[idx];
        }
    } else {
        cf* sA = (cf*)(sPool + 33792);
        cf* Tc = (cf*)(sPool + 66560);
        for (int idx = tid; idx < 4096; idx += 256)
            sA[idx] = mkc(Ar[idx], Ai[idx]);
        __syncthreads();
        for (int jb = 0; jb < 8; jb++){
            int j0 = jb*8;
            #pragma unroll
            for (int rep = 0; rep < 2; rep++){
                int idx = tid + rep*256;
                int p = idx >> 3, jc = idx & 7;
                cf acc = mkc(0,0);
                for (int q = 0; q < 64; q++){
                    cf rv = mkc(Rr[p*64+q], Ri[p*64+q]);
                    cmad(acc, rv, sA[q*64 + j0 + jc]);
                }
                Tc[idx] = acc;
            }
            __syncthreads();
            #pragma unroll
            for (int rep = 0; rep < 2; rep++){
                int idx = tid + rep*256;
                int i2 = idx >> 3, jc = idx & 7;
                cf acc = mkc(0,0);
                for (int p = 0; p < 64; p++)
                    cmadc(acc, sA[p*64+i2], Tc[p*8+jc]);
                sMm[i2*MM_S + j0 + jc] = acc;
            }
            __syncthreads();
        }
        __syncthreads();
    }

    cf fsf[4]; cf ssw = mkc(0.f, 0.f);
    {
        const float* hr = Hre + (size_t)b*512;
        const float* hi = Him + (size_t)b*512;
        for (int idx = tid; idx < 512; idx += 256){
            int m = idx >> 6, n = idx & 63;
            sH[m*H_S+n] = mkc(hr[idx], hi[idx]);
        }
        const float* fr = F0re + (size_t)b*1024;
        const float* fi = F0im + (size_t)b*1024;
        for (int idx = tid; idx < 1024; idx += 256){
            int n = idx >> 4, r = idx & 15;
            float re = fr[idx], im = fi[idx];
            float mag = hypotf(re, im);
            cf f = (mag > 1e-12f) ? mkc(re/mag, im/mag) : mkc(0.f, 0.f);
            sF[n*F_S+r] = f;
            sFT[r*FT_S+n] = f;
        }
        if (tid < 128)
            sW[tid] = mkc(W0re[(size_t)b*128 + tid], W0im[(size_t)b*128 + tid]);
        #pragma unroll
        for (int rep = 0; rep < 4; rep++) fsf[rep] = mkc(0.f, 0.f);
    }
    __syncthreads();

    uRefresh(sH, sFT, sU, tid);
    {
        int k = tid & 7, nb = tid >> 3;
        cf wcol[16];
        #pragma unroll
        for (int r = 0; r < 16; r++) wcol[r] = sW[r*8+k];
        float part = 0.f;
        #pragma unroll
        for (int rep = 0; rep < 2; rep++){
            int n = nb + rep*32;
            const float4* fr4 = (const float4*)(sF + n*F_S);
            cf acc = mkc(0,0);
            #pragma unroll
            for (int q = 0; q < 8; q++){
                float4 v = fr4[q];
                cmad(acc, lo4(v), wcol[2*q]); cmad(acc, hi4(v), wcol[2*q+1]);
            }
            sFW[n*8+k] = acc;
            part += acc.x*acc.x + acc.y*acc.y;
        }
        float pw0 = blockReduceSum(part, sRedS+0, tid);
        float s0 = sqrtf(Pt / pw0);
        if (tid < 128){ cf w = sW[tid]; sW[tid] = mkc(w.x*s0, w.y*s0); }
    }
    computeMF_T(sMm, sFT, sMF, tid);
    __syncthreads();

    float sp = 1.0f, sp2 = 1.0f;

    for (int ii = 0; ii < n_outer; ii++){
        {
            int i = tid >> 4, jx = tid & 15;
            cf acc = mkc(0,0);
            #pragma unroll
            for (int k = 0; k < 8; k++) cmad_bc(acc, sW[i*8+k], sW[jx*8+k]);
            sV[i*V_S+jx] = acc;
        }
        __syncthreads();

        for (int jj = 0; jj < n_inner; jj++){
            const int j = tid & 15, nb = tid >> 4;
            cf vrow[16];
            {
                const float4* vp = (const float4*)(sV + j*V_S);
                #pragma unroll
                for (int q = 0; q < 8; q++){
                    float4 v = vp[q];
                    vrow[2*q] = lo4(v); vrow[2*q+1] = hi4(v);
                }
            }
            float ptr_ = 0.f;
            cf G[4];
            #pragma unroll
            for (int rep = 0; rep < 4; rep++){
                int n = nb + rep*16;
                const float4* mr = (const float4*)(sMF + n*F_S);
                cf acc = mkc(0,0);
                #pragma unroll
                for (int q = 0; q < 8; q++){
                    float4 v = mr[q];
                    cmad_bc(acc, lo4(v), vrow[2*q]); cmad_bc(acc, hi4(v), vrow[2*q+1]);
                }
                G[rep] = acc;
                cf f = sF[n*F_S+j];
                ptr_ += f.x*acc.x + f.y*acc.y;
            }
            if (tid < 128){
                int m = tid >> 4;
                const float4* up = (const float4*)(sU + m*U_S);
                cf t2 = mkc(0,0);
                #pragma unroll
                for (int q = 0; q < 8; q++){
                    float4 uv = up[q];
                    cmad_bc(t2, lo4(uv), vrow[2*q]); cmad_bc(t2, hi4(uv), vrow[2*q+1]);
                }
                cf u = sU[m*U_S+j];
                float qv = t2.x*u.x + t2.y*u.y;
                cf c = mkc(0,0); cmad(c, u, sW[j*8+m]);
                #pragma unroll
                for (int mask = 8; mask >= 1; mask >>= 1){
                    qv  += __shfl_xor(qv,  mask, 16);
                    c.x += __shfl_xor(c.x, mask, 16);
                    c.y += __shfl_xor(c.y, mask, 16);
                }
                float cc = c.x*c.x + c.y*c.y;
                float inv1 = 1.0f/(LN2F*(sp2*qv + 1.0f) + 1e-4f);
                float inv2 = 1.0f/(LN2F*(sp2*(qv - cc) + 1.0f) + 1e-4f);
                float a = inv1 - inv2;
                cf ci = mkc(c.x*inv2, c.y*inv2);
                cf row = mkc(t2.x*a, t2.y*a);
                cmad_bc(row, ci, sW[j*8+m]);
                sRow[tid] = row;
            }
            if (jj > 0) ratesWave3(sU, sW, sp2, &sRateValS, tid);
            float tr = blockReduceSum(ptr_, sRedS+0, tid);
            if (jj > 0 && tid == 0){
                int tt = ii*(n_inner+1) + jj;
                size_t base = (size_t)b*nt;
                outR[base + tt] = sRateValS;
                outC[base + tt] = 1.0f/(cxi*(sp2*tr) + 1e-12f);
            }
            {
                float hinv = 0.5f/(sp*tr);
                cf rowj[8];
                #pragma unroll
                for (int m = 0; m < 8; m++){
                    cf r = sRow[m*16+j];
                    rowj[m] = mkc(sp*r.x, sp*r.y);
                }
                #pragma unroll
                for (int rep = 0; rep < 4; rep++){
                    int n = nb + rep*16;
                    cf g = mkc(G[rep].x*hinv, G[rep].y*hinv);
                    #pragma unroll
                    for (int m = 0; m < 8; m++) cmad(g, sH[m*H_S+n], rowj[m]);
                    cf sf = fsf[rep];
                    sf.x = BETA_*sf.x + OMB_*g.x;
                    sf.y = BETA_*sf.y + OMB_*g.y;
                    fsf[rep] = sf;
                    cf d = csqrtf2(sf); d.x += EPS_;
                    cf upd = cdiv(g, d);
                    cf f = sF[n*F_S+j];
                    cf fn = mkc(fmaf(ETAF_, upd.x, sp*f.x), fmaf(ETAF_, upd.y, sp*f.y));
                    sF[n*F_S+j] = fn;
                    sFT[j*FT_S+n] = fn;
                }
            }
            __syncthreads();

            computeMF_T(sMm, sFT, sMF, tid);
            float part;
            {
                int k = tid & 7, nb2 = tid >> 3;
                cf wcol[16];
                #pragma unroll
                for (int r = 0; r < 16; r++) wcol[r] = sW[r*8+k];
                part = 0.f;
                #pragma unroll
                for (int rep = 0; rep < 2; rep++){
                    int n = nb2 + rep*32;
                    const float4* fr4 = (const float4*)(sF + n*F_S);
                    cf acc = mkc(0,0);
                    #pragma unroll
                    for (int q = 0; q < 8; q++){
                        float4 v = fr4[q];
                        cmad(acc, lo4(v), wcol[2*q]); cmad(acc, hi4(v), wcol[2*q+1]);
                    }
                    sFW[n*8+k] = acc;
                    part += acc.x*acc.x + acc.y*acc.y;
                }
            }
            uRefresh(sH, sFT, sU, tid);
            float pw = blockReduceSum(part, sRedS+4, tid);
            float s = sqrtf(Pt / pw);
            sp = s; sp2 = s*s;

            if (jj == n_inner-1){
                float ptrl = 0.f;
                #pragma unroll
                for (int rep = 0; rep < 4; rep++){
                    int n = nb + rep*16;
                    const float4* mr = (const float4*)(sMF + n*F_S);
                    cf acc = mkc(0,0);
                    #pragma unroll
                    for (int q = 0; q < 8; q++){
                        float4 v = mr[q];
                        cmad_bc(acc, lo4(v), vrow[2*q]); cmad_bc(acc, hi4(v), vrow[2*q+1]);
                    }
                    cf f = sF[n*F_S+j];
                    ptrl += f.x*acc.x + f.y*acc.y;
                }
                ratesWave3(sU, sW, sp2, &sRateValS, tid);
                float trl = blockReduceSum(ptrl, sRedS+8, tid);
                if (tid == 0){
                    int tt = ii*(n_inner+1) + n_inner;
                    size_t base = (size_t)b*nt;
                    outR[base + tt] = sRateValS;
                    outC[base + tt] = 1.0f/(cxi*(sp2*trl) + 1e-12f);
                }
            }
        }

        const int j = tid & 15, nb = tid >> 4;
        {
            #pragma unroll
            for (int rep = 0; rep < 4; rep++){
                int n = nb + rep*16;
                cf f = sF[n*F_S+j];
                float mag = hypotf(f.x, f.y);
                cf fp = (sp*mag > 1e-12f) ? mkc(f.x/mag, f.y/mag) : mkc(0.f, 0.f);
                sF[n*F_S+j] = fp;
                sFT[j*FT_S+n] = fp;
            }
            sp = 1.0f; sp2 = 1.0f;
        }
        __syncthreads();
        computeMF_T(sMm, sFT, sMF, tid);
        uRefresh(sH, sFT, sU, tid);
        __syncthreads();
        float ptr2;
        {
            int i = tid >> 4;
            const float4* fti = (const float4*)(sFT + i*FT_S);
            cf acc = mkc(0,0);
            #pragma unroll
            for (int q = 0; q < 32; q++){
                float4 fv = fti[q];
                cmadc(acc, lo4(fv), sMF[(2*q  )*F_S+j]);
                cmadc(acc, hi4(fv), sMF[(2*q+1)*F_S+j]);
            }
            sFHMF[i*17+j] = acc;
            cf v = sV[j*V_S+i];
            ptr2 = acc.x*v.x - acc.y*v.y;
        }
        if (tid < 128){
            int m = tid >> 4, r = tid & 15;
            cf u_mr = sU[m*U_S+r];
            const float4* up = (const float4*)(sU + m*U_S);
            cf t2 = mkc(0,0);
            #pragma unroll
            for (int q = 0; q < 8; q++){
                float4 uv = up[q];
                cmad_cc(t2, sV[(2*q)*V_S+r],   lo4(uv));
                cmad_cc(t2, sV[(2*q+1)*V_S+r], hi4(uv));
            }
            float trm = u_mr.x*t2.x - u_mr.y*t2.y;
            cf a = mkc(0,0); cmad(a, u_mr, sW[r*8+m]);
            #pragma unroll
            for (int mask = 8; mask >= 1; mask >>= 1){
                trm += __shfl_xor(trm, mask, 16);
                a.x += __shfl_xor(a.x, mask, 16);
                a.y += __shfl_xor(a.y, mask, 16);
            }
            if (r == 0){
                float invd = 1.0f/(LN2F*(trm + 1.0f)*8.0f);
                sCoefC[m] = mkc(a.x*invd, a.y*invd);
            }
        }
        float trW = blockReduceSum(ptr2, sRedS+0, tid);
        cf gw = mkc(0,0);
        if (tid < 128){
            int i2 = tid >> 3, mm = tid & 7;
            cf acc = mkc(0,0);
            #pragma unroll
            for (int j2 = 0; j2 < 16; j2++) cmad(acc, sFHMF[i2*17+j2], sW[j2*8+mm]);
            float hinv = 0.5f / trW;
            gw = mkc(acc.x*hinv, acc.y*hinv);
            cmadc(gw, sU[mm*U_S+i2], sCoefC[mm]);
        }
        __syncthreads();
        if (tid < 128){
            cf sw = ssw;
            sw.x = BETA_*sw.x + OMB_*gw.x;
            sw.y = BETA_*sw.y + OMB_*gw.y;
            ssw = sw;
            cf d = csqrtf2(sw); d.x += EPS_;
            cf upd = cdiv(gw, d);
            cf w = sW[tid];
            w.x = fmaf(ETAW_, upd.x, w.x);
            w.y = fmaf(ETAW_, upd.y, w.y);
            sW[tid] = w;
        }
        __syncthreads();
        float part2;
        {
            int k = tid & 7, nb2 = tid >> 3;
            cf wcol[16];
            #pragma unroll
            for (int r = 0; r < 16; r++) wcol[r] = sW[r*8+k];
            part2 = 0.f;
            #pragma unroll
            for (int rep = 0; rep < 2; rep++){
                int n = nb2 + rep*32;
                const float4* fr4 = (const float4*)(sF + n*F_S);
                cf acc = mkc(0,0);
                #pragma unroll
                for (int q = 0; q < 8; q++){
                    float4 v = fr4[q];
                    cmad(acc, lo4(v), wcol[2*q]); cmad(acc, hi4(v), wcol[2*q+1]);
                }
                sFW[n*8+k] = acc;
                part2 += acc.x*acc.x + acc.y*acc.y;
            }
        }
        float ptrc2;
        {
            int k = tid & 7, nb2 = tid >> 3;
            cf wcol[16];
            #pragma unroll
            for (int r = 0; r < 16; r++) wcol[r] = sW[r*8+k];
            ptrc2 = 0.f;
            #pragma unroll
            for (int rep = 0; rep < 2; rep++){
                int n = nb2 + rep*32;
                const float4* mr = (const float4*)(sMF + n*F_S);
                cf acc = mkc(0,0);
                #pragma unroll
                for (int q = 0; q < 8; q++){
                    float4 v = mr[q];
                    cmad(acc, lo4(v), wcol[2*q]); cmad(acc, hi4(v), wcol[2*q+1]);
                }
                cf fw = sFW[n*8+k];
                ptrc2 += fw.x*acc.x + fw.y*acc.y;
            }
        }
        float2 pr = blockReduceSum2(part2, ptrc2, sRedS+4, sRedS+8, tid);
        float s2 = sqrtf(Pt / pr.x);
        float s2sq = s2*s2;
        ratesWave3(sU, sW, s2sq, &sRateValS, tid);
        __syncthreads();
        if (tid < 128){
            cf w = sW[tid];
            sW[tid] = mkc(w.x*s2, w.y*s2);
        }
        if (tid == 0){
            int tt = ii*(n_inner+1);
            size_t base = (size_t)b*nt;
            outR[base + tt] = sRateValS;
            outC[base + tt] = 1.0f/(cxi*(s2sq*pr.y) + 1e-12f);
        }
        __syncthreads();
    }

    if (cplx){
        int j = tid & 15, nb = tid >> 4;
        #pragma unroll
        for (int rep = 0; rep < 4; rep++){
            int n = nb + rep*16;
            cf f = sF[n*F_S+j];
            size_t o = ((size_t)b*1024 + (size_t)(tid + rep*256))*2;
            outF[o]   = f.x;
            outF[o+1] = f.y;
        }
        if (tid < 128){
            cf w = sW[tid];
            size_t o = ((size_t)b*128 + tid)*2;
            outW[o]   = w.x;
            outW[o+1] = w.y;
        }
    } else {
        int j = tid & 15, nb = tid >> 4;
        #pragma unroll
        for (int rep = 0; rep < 4; rep++){
            int n = nb + rep*16;
            outF[(size_t)b*1024 + (size_t)(tid + rep*256)] = sF[n*F_S+j].x;
        }
        if (tid < 128)
            outW[(size_t)b*128 + tid] = sW[tid].x;
    }
}

extern "C" void kernel_launch(void* const* d_in, const int* in_sizes, int n_in,
                              void* d_out, int out_size, void* d_ws, size_t ws_size,
                              hipStream_t stream)
{
    (void)n_in;
    int B = in_sizes[0] / 512;   // A*B*Mu*N / (8*64)

    long S = (long)out_size;
    long numI = S - 2304L*B;
    long numR = S - 1152L*B;
    bool okI = (numI > 0) && (numI % (2L*B) == 0) && (numI/(2L*B) >= 1) && (numI/(2L*B) <= 256);
    bool okR = (numR > 0) && (numR % (2L*B) == 0) && (numR/(2L*B) >= 1) && (numR/(2L*B) <= 256);
    int cplx = okI ? 1 : (okR ? 0 : 1);

    const float* Ar = (const float*)d_in[6];
    const float* Ai = (const float*)d_in[7];
    const float* Rr = (const float*)d_in[8];
    const float* Ri = (const float*)d_in[9];

    cf* Mm = nullptr;
    if (d_ws != nullptr && ws_size >= 65536){
        Mm = (cf*)d_ws;
        pga_prep<<<1, 256, 0, stream>>>(Ar, Ai, Rr, Ri, Mm);
    }

    // Probe launchability of the 152.6 KB-LDS mega-kernel (deterministic, capture-safe).
    size_t dynLds = (size_t)MEGA_LDS;
    (void)hipFuncSetAttribute(reinterpret_cast<const void*>(pga_main4),
                              hipFuncAttributeMaxDynamicSharedMemorySize, (int)dynLds);
    int occBlocks = 0;
    hipError_t occErr = hipOccupancyMaxActiveBlocksPerMultiprocessor(
        &occBlocks, reinterpret_cast<const void*>(pga_main4), 1024, dynLds);
    bool use4 = (occErr == hipSuccess && occBlocks >= 1);

    if (use4){
        int nblk = (B + 3) / 4;
        pga_main4<<<nblk, 1024, dynLds, stream>>>(
            (const float*)d_in[0], (const float*)d_in[1],
            (const float*)d_in[2], (const float*)d_in[3],
            (const float*)d_in[4], (const float*)d_in[5],
            Ar, Ai, Rr, Ri,
            Mm,
            (const float*)d_in[10],
            (const int*)d_in[11], (const int*)d_in[12], (const int*)d_in[13],
            (float*)d_out, B, cplx);
    } else {
        pga_main<<<B, 256, 0, stream>>>(
            (const float*)d_in[0], (const float*)d_in[1],
            (const float*)d_in[2], (const float*)d_in[3],
            (const float*)d_in[4], (const float*)d_in[5],
            Ar, Ai, Rr, Ri,
            Mm,
            (const float*)d_in[10],
            (const int*)d_in[11], (const int*)d_in[12], (const int*)d_in[13],
            (float*)d_out, B, cplx);
    }
}